// Round 5
// baseline (517.353 us; speedup 1.0000x reference)
//
#include <hip/hip_runtime.h>
#include <math.h>
#include <stdint.h>

// Problem constants (B=2, S=1024, H=2048, E=16, K=4, CAP=768)
#define NTOK 2048
#define HDIM 2048
#define HHALF 1024
#define EDIM 16
#define CAPV 768
#define TOPK 4
#define GK 2048        // K is 2048 for every GEMM in this problem

typedef __bf16 bf16x8 __attribute__((ext_vector_type(8)));
typedef __bf16 bf16x4 __attribute__((ext_vector_type(4)));
typedef float f32x4 __attribute__((ext_vector_type(4)));

// =====================================================================
// Stage-A GEMM: 256x256 tile, BK=32, 512 thr (8 waves of 128x64),
// double-buffered 128KB LDS, counted-vmcnt prefetch (never vmcnt(0) in
// the main loop), 3-term bf16 split (Ah*Bh + Ah*Bl + Al*Bh).
// LDS chunk swizzle: chunk ^= (row>>1)&3 (verified uniform bank-slot
// coverage); applied on BOTH the global source and the ds_read offsets
// (rule #21: linear gload_lds dest + pre-swizzled source + swizzled read).
// =====================================================================

struct GJobA {
  const __bf16 *Ah, *Al, *Wh, *Wl;   // A [M][K] split; W^T [N][K] split
  const float* bias;
  float* Cf; __bf16 *Ch, *Cl;
  int relu, N, blk0;
};
struct GJobsA { GJobA j[6]; };

#define BKA 32
#define NTA 64   // 2048 / 32 K-tiles

__global__ __launch_bounds__(512, 2) void gemm_bigA(GJobsA P) {
  // [buf][array: Ah,Al,Bh,Bl][256 rows * 32 k]  = 2*4*16KB = 128 KB
  __shared__ __align__(16) __bf16 lds[2][4][256 * BKA];

  const int tid = threadIdx.x;
  const int wid = tid >> 6, lane = tid & 63;
  const int lane15 = lane & 15, c0 = lane >> 4;

  // job select from flat block id
  const int bid = blockIdx.x;
  int ji = 0;
#pragma unroll
  for (int k = 1; k < 6; ++k)
    if (bid >= P.j[k].blk0) ji = k;
  const GJobA J = P.j[ji];
  const int local = bid - J.blk0;
  const int nbx = J.N >> 8;                 // 8 or 4 (power of two)
  const int bx = local & (nbx - 1);
  const int by = local / nbx;
  const int m0 = by * 256, n0 = bx * 256;

  const int wr = wid >> 2, wc = wid & 3;    // 2 (M) x 4 (N) waves -> 128x64 each

  // staging constants: per thread 2 slots per array (slots tid, tid+512)
  int srow[2], soff[2];
#pragma unroll
  for (int h = 0; h < 2; ++h) {
    int s = tid + h * 512;
    int row = s >> 2;
    srow[h] = row;
    soff[h] = ((s & 3) ^ ((row >> 1) & 3)) * 8;   // swizzled source chunk (elems)
  }

  // fragment ds_read byte offsets (constant across tiles)
  int offB[4], offA[2][4];
#pragma unroll
  for (int ni = 0; ni < 4; ++ni) {
    int rb = wc * 64 + ni * 16 + lane15;
    offB[ni] = rb * 64 + ((c0 ^ ((rb >> 1) & 3)) << 4);
  }
#pragma unroll
  for (int mh = 0; mh < 2; ++mh)
#pragma unroll
    for (int i = 0; i < 4; ++i) {
      int ra = wr * 128 + mh * 64 + i * 16 + lane15;
      offA[mh][i] = ra * 64 + ((c0 ^ ((ra >> 1) & 3)) << 4);
    }

#define STAGE_ARR(gptr, grow0, k0, larr)                                       \
  {                                                                            \
    _Pragma("unroll") for (int h = 0; h < 2; ++h) {                            \
      const __bf16* _src =                                                     \
          (gptr) + (size_t)((grow0) + srow[h]) * GK + (k0) + soff[h];          \
      __builtin_amdgcn_global_load_lds(                                        \
          (const __attribute__((address_space(1))) uint32_t*)_src,             \
          (__attribute__((address_space(3))) uint32_t*)((larr) +               \
                                                        (wid * 64 + h * 512) * 8), \
          16, 0, 0);                                                           \
    }                                                                          \
  }

#define STAGE_TILE(buf, k0)                                                    \
  {                                                                            \
    STAGE_ARR(J.Ah, m0, (k0), lds[buf][0]);                                    \
    STAGE_ARR(J.Al, m0, (k0), lds[buf][1]);                                    \
    STAGE_ARR(J.Wh, n0, (k0), lds[buf][2]);                                    \
    STAGE_ARR(J.Wl, n0, (k0), lds[buf][3]);                                    \
  }

  f32x4 acc[8][4];
#pragma unroll
  for (int i = 0; i < 8; ++i)
#pragma unroll
    for (int j = 0; j < 4; ++j) acc[i][j] = (f32x4){0.f, 0.f, 0.f, 0.f};

  // prologue: stage tile 0
  STAGE_TILE(0, 0);

  for (int t = 0; t < NTA; ++t) {
    const int cur = t & 1;
    if (t + 1 < NTA) {
      STAGE_TILE(cur ^ 1, (t + 1) * BKA);          // 8 loads in flight
      asm volatile("s_waitcnt vmcnt(8)" ::: "memory");   // tile t landed
    } else {
      asm volatile("s_waitcnt vmcnt(0)" ::: "memory");
    }
    __builtin_amdgcn_s_barrier();
    __builtin_amdgcn_sched_barrier(0);             // pin reads below barrier

    const char* cAh = (const char*)lds[cur][0];
    const char* cAl = (const char*)lds[cur][1];
    const char* cBh = (const char*)lds[cur][2];
    const char* cBl = (const char*)lds[cur][3];

    bf16x8 bh[4], bl[4];
#pragma unroll
    for (int ni = 0; ni < 4; ++ni) {
      bh[ni] = *(const bf16x8*)(cBh + offB[ni]);
      bl[ni] = *(const bf16x8*)(cBl + offB[ni]);
    }
#pragma unroll
    for (int mh = 0; mh < 2; ++mh) {
      bf16x8 ah[4], al[4];
#pragma unroll
      for (int i = 0; i < 4; ++i) {
        ah[i] = *(const bf16x8*)(cAh + offA[mh][i]);
        al[i] = *(const bf16x8*)(cAl + offA[mh][i]);
      }
#pragma unroll
      for (int mi = 0; mi < 4; ++mi)
#pragma unroll
        for (int ni = 0; ni < 4; ++ni) {
          acc[mh * 4 + mi][ni] = __builtin_amdgcn_mfma_f32_16x16x32_bf16(
              ah[mi], bh[ni], acc[mh * 4 + mi][ni], 0, 0, 0);
          acc[mh * 4 + mi][ni] = __builtin_amdgcn_mfma_f32_16x16x32_bf16(
              ah[mi], bl[ni], acc[mh * 4 + mi][ni], 0, 0, 0);
          acc[mh * 4 + mi][ni] = __builtin_amdgcn_mfma_f32_16x16x32_bf16(
              al[mi], bh[ni], acc[mh * 4 + mi][ni], 0, 0, 0);
        }
    }
    __builtin_amdgcn_sched_barrier(0);             // pin reads above barrier
    __builtin_amdgcn_s_barrier();                  // buf free for next stage
  }

  // epilogue: C/D layout col=lane&15, row=(lane>>4)*4+reg [m89]
#pragma unroll
  for (int mh = 0; mh < 2; ++mh)
#pragma unroll
    for (int mi = 0; mi < 4; ++mi)
#pragma unroll
      for (int ni = 0; ni < 4; ++ni) {
        int col = n0 + wc * 64 + ni * 16 + lane15;
        float bv = J.bias[col];
        f32x4 v = acc[mh * 4 + mi][ni];
#pragma unroll
        for (int j = 0; j < 4; ++j) {
          int row = m0 + wr * 128 + mh * 64 + mi * 16 + c0 * 4 + j;
          float x = v[j] + bv;
          if (J.relu) x = fmaxf(x, 0.0f);
          size_t o = (size_t)row * J.N + col;
          if (J.Cf) J.Cf[o] = x;
          if (J.Ch) {
            __bf16 hh = (__bf16)x;
            J.Ch[o] = hh;
            J.Cl[o] = (__bf16)(x - (float)hh);
          }
        }
      }
#undef STAGE_ARR
#undef STAGE_TILE
}

// =====================================================================
// Stage-B' GEMM: the proven 128x128 / BK=64 / 4-wave kernel (round 4).
// =====================================================================
#define BKT 64

struct GJob {
  const __bf16* Ah; const __bf16* Al;
  const __bf16* Wh; const __bf16* Wl;
  const float* bias;
  float* Cf;
  __bf16* Ch; __bf16* Cl;
  int relu; int N; int blk0;
};
struct GJobs { GJob j[4]; int njobs; };

__device__ __forceinline__ void stage_tile(const __bf16* __restrict__ g,
                                           int grow0, int k0,
                                           __bf16* lbase, int wid, int lane) {
  int r_in = lane >> 3;
  int swz_elems = ((lane & 7) ^ r_in) << 3;
#pragma unroll
  for (int i = 0; i < 4; ++i) {
    int row0 = wid * 32 + i * 8;
    const __bf16* src = g + (size_t)(grow0 + row0 + r_in) * GK + k0 + swz_elems;
    __builtin_amdgcn_global_load_lds(
        (const __attribute__((address_space(1))) uint32_t*)src,
        (__attribute__((address_space(3))) uint32_t*)(lbase + row0 * BKT),
        16, 0, 0);
  }
}

__global__ __launch_bounds__(256) void gemm_split(GJobs P) {
  __shared__ __align__(16) __bf16 lds[4 * 128 * BKT];
  __bf16* ldsAh = lds;
  __bf16* ldsAl = lds + 8192;
  __bf16* ldsBh = lds + 16384;
  __bf16* ldsBl = lds + 24576;
  const char* cAh = (const char*)ldsAh;
  const char* cAl = (const char*)ldsAl;
  const char* cBh = (const char*)ldsBh;
  const char* cBl = (const char*)ldsBl;

  const int bid = blockIdx.x;
  int ji = 0;
#pragma unroll
  for (int k = 1; k < 4; ++k)
    if (k < P.njobs && bid >= P.j[k].blk0) ji = k;
  const GJob J = P.j[ji];
  const int local = bid - J.blk0;
  const int nbx = J.N >> 7;
  const int bx = local & (nbx - 1);
  const int by = local / nbx;
  const int m0 = by * 128;
  const int n0 = bx * 128;

  const int tid = threadIdx.x;
  const int wid = tid >> 6;
  const int lane = tid & 63;
  const int lane15 = lane & 15;
  const int c0 = lane >> 4;
  const int wr = wid >> 1;
  const int wc = wid & 1;

  int offA[4][2], offB[4][2];
#pragma unroll
  for (int i = 0; i < 4; ++i) {
    int ra = wr * 64 + i * 16 + lane15;
    int rb = wc * 64 + i * 16 + lane15;
#pragma unroll
    for (int ks = 0; ks < 2; ++ks) {
      offA[i][ks] = ra * 128 + (((ks * 4 + c0) ^ (ra & 7)) << 4);
      offB[i][ks] = rb * 128 + (((ks * 4 + c0) ^ (rb & 7)) << 4);
    }
  }

  f32x4 acc[4][4];
#pragma unroll
  for (int i = 0; i < 4; ++i)
#pragma unroll
    for (int j = 0; j < 4; ++j) acc[i][j] = (f32x4){0.f, 0.f, 0.f, 0.f};

  for (int k0 = 0; k0 < GK; k0 += BKT) {
    stage_tile(J.Ah, m0, k0, ldsAh, wid, lane);
    stage_tile(J.Al, m0, k0, ldsAl, wid, lane);
    stage_tile(J.Wh, n0, k0, ldsBh, wid, lane);
    stage_tile(J.Wl, n0, k0, ldsBl, wid, lane);
    __syncthreads();
#pragma unroll
    for (int ks = 0; ks < 2; ++ks) {
      bf16x8 ah[4], al[4], bh[4], bl[4];
#pragma unroll
      for (int i = 0; i < 4; ++i) {
        ah[i] = *(const bf16x8*)(cAh + offA[i][ks]);
        al[i] = *(const bf16x8*)(cAl + offA[i][ks]);
        bh[i] = *(const bf16x8*)(cBh + offB[i][ks]);
        bl[i] = *(const bf16x8*)(cBl + offB[i][ks]);
      }
#pragma unroll
      for (int mi = 0; mi < 4; ++mi)
#pragma unroll
        for (int ni = 0; ni < 4; ++ni) {
          acc[mi][ni] = __builtin_amdgcn_mfma_f32_16x16x32_bf16(
              ah[mi], bh[ni], acc[mi][ni], 0, 0, 0);
          acc[mi][ni] = __builtin_amdgcn_mfma_f32_16x16x32_bf16(
              ah[mi], bl[ni], acc[mi][ni], 0, 0, 0);
          acc[mi][ni] = __builtin_amdgcn_mfma_f32_16x16x32_bf16(
              al[mi], bh[ni], acc[mi][ni], 0, 0, 0);
        }
    }
    __syncthreads();
  }

#pragma unroll
  for (int mi = 0; mi < 4; ++mi) {
#pragma unroll
    for (int ni = 0; ni < 4; ++ni) {
      int col = n0 + wc * 64 + ni * 16 + lane15;
      float bv = J.bias[col];
      f32x4 v = acc[mi][ni];
#pragma unroll
      for (int j = 0; j < 4; ++j) {
        int row = m0 + wr * 64 + mi * 16 + c0 * 4 + j;
        float x = v[j] + bv;
        if (J.relu) x = fmaxf(x, 0.0f);
        size_t o = (size_t)row * J.N + col;
        if (J.Cf) J.Cf[o] = x;
        if (J.Ch) {
          __bf16 hh = (__bf16)x;
          J.Ch[o] = hh;
          J.Cl[o] = (__bf16)(x - (float)hh);
        }
      }
    }
  }
}

// ---------------- fp32 -> (hi, lo) bf16 split, 4 inputs batched ----------------
struct SJob { const float* in; __bf16* h; __bf16* l; };
#define SPLIT_BLKS 4096
__global__ __launch_bounds__(256) void split4(SJob a, SJob b, SJob c, SJob d) {
  int job = blockIdx.x >> 12;
  SJob J = (job == 0) ? a : (job == 1) ? b : (job == 2) ? c : d;
  int i = (blockIdx.x & 4095) * 256 + threadIdx.x;
  float4 v = ((const float4*)J.in)[i];
  bf16x4 hv, lv;
  hv.x = (__bf16)v.x; lv.x = (__bf16)(v.x - (float)hv.x);
  hv.y = (__bf16)v.y; lv.y = (__bf16)(v.y - (float)hv.y);
  hv.z = (__bf16)v.z; lv.z = (__bf16)(v.z - (float)hv.z);
  hv.w = (__bf16)v.w; lv.w = (__bf16)(v.w - (float)hv.w);
  ((bf16x4*)J.h)[i] = hv;
  ((bf16x4*)J.l)[i] = lv;
}

// ------- W[2048][Nd] fp32 -> W^T hi/lo bf16 [Nd][2048], 6 weights batched -------
struct TJob { const float* W; __bf16* Th; __bf16* Tl; int Nd; };
struct TJobs { TJob j[6]; };
__global__ __launch_bounds__(256) void tsplit(TJobs P) {
  const TJob J = P.j[blockIdx.z];
  int n0 = blockIdx.x * 32;
  if (n0 >= J.Nd) return;
  int k0 = blockIdx.y * 32;
  __shared__ float t[32][33];
  int tx = threadIdx.x & 31, ty = threadIdx.x >> 5;
#pragma unroll
  for (int i = 0; i < 4; ++i) {
    int kk = ty + i * 8;
    t[kk][tx] = J.W[(size_t)(k0 + kk) * J.Nd + n0 + tx];
  }
  __syncthreads();
#pragma unroll
  for (int i = 0; i < 4; ++i) {
    int nn = ty + i * 8;
    float v = t[tx][nn];
    __bf16 hh = (__bf16)v;
    size_t o = (size_t)(n0 + nn) * GK + k0 + tx;
    J.Th[o] = hh;
    J.Tl[o] = (__bf16)(v - (float)hh);
  }
}

// -------- prebias: v[n] = sum_k b2[k]*W1[k][n] + b1[n]   (N=1024, K=2048) -----
__global__ __launch_bounds__(256) void prebias(
    const float* __restrict__ b2,
    const float* __restrict__ W1a, const float* __restrict__ b1a, float* va,
    const float* __restrict__ W1b, const float* __restrict__ b1b, float* vb) {
  const float* W1 = blockIdx.y ? W1b : W1a;
  const float* b1 = blockIdx.y ? b1b : b1a;
  float* v = blockIdx.y ? vb : va;
  int n = blockIdx.x * 256 + threadIdx.x;
  float acc = b1[n];
#pragma unroll 8
  for (int k = 0; k < GK; ++k) acc = fmaf(b2[k], W1[(size_t)k * HHALF + n], acc);
  v[n] = acc;
}

// ---------------- Skinny logits, 5 routers batched ----------------
struct LJob { const float* Y; const float* W2; const float* b2; float* L; int K; };
struct LJobs { LJob j[5]; };
__global__ __launch_bounds__(256) void logits_kernel(LJobs P) {
  const LJob J = P.j[blockIdx.x >> 8];
  const int blk = blockIdx.x & 255;
  const int tid = threadIdx.x;
  const int wid = tid >> 6, lane = tid & 63;
  const int e = lane & 15;
  const int kq = lane >> 4;
  const int tok0 = blk * 8 + wid * 2;
  const float* y0 = J.Y + (size_t)tok0 * J.K;
  const float* y1 = y0 + J.K;
  const int KQ = J.K >> 2;
  const int kbase = kq * KQ;
  float a0 = 0.f, a1 = 0.f;
#pragma unroll 8
  for (int k = 0; k < KQ; ++k) {
    int kk = kbase + k;
    float w = J.W2[(size_t)kk * EDIM + e];
    a0 = fmaf(y0[kk], w, a0);
    a1 = fmaf(y1[kk], w, a1);
  }
  a0 += __shfl_xor(a0, 16); a0 += __shfl_xor(a0, 32);
  a1 += __shfl_xor(a1, 16); a1 += __shfl_xor(a1, 32);
  if (lane < 16) {
    float b = J.b2[e];
    J.L[(size_t)tok0 * EDIM + e] = a0 + b;
    J.L[(size_t)(tok0 + 1) * EDIM + e] = a1 + b;
  }
}

// ---------------- Router finalize ----------------
__device__ __forceinline__ void softmax16(const float* __restrict__ L, float* __restrict__ p) {
  float v[16];
  *(float4*)&v[0]  = *(const float4*)&L[0];
  *(float4*)&v[4]  = *(const float4*)&L[4];
  *(float4*)&v[8]  = *(const float4*)&L[8];
  *(float4*)&v[12] = *(const float4*)&L[12];
  float m = v[0];
#pragma unroll
  for (int e = 1; e < 16; ++e) m = fmaxf(m, v[e]);
  float s = 0.0f;
#pragma unroll
  for (int e = 0; e < 16; ++e) { v[e] = expf(v[e] - m); s += v[e]; }
  float inv = 1.0f / s;
#pragma unroll
  for (int e = 0; e < 16; ++e) p[e] = v[e] * inv;
}

__global__ __launch_bounds__(256) void finalize_kernel(
    const float* __restrict__ Lg, const float* __restrict__ Lsi,
    const float* __restrict__ Lsg, const float* __restrict__ Lsc,
    const float* __restrict__ Lsb,
    float* __restrict__ dispatch, float* __restrict__ combine,
    float* __restrict__ router_probs, float* __restrict__ mean_acc) {
  __shared__ float sm[EDIM];
  int tid = threadIdx.x;
  if (tid < EDIM) sm[tid] = 0.0f;
  __syncthreads();

  int tok = blockIdx.x * 256 + tid;
  float pg[16], ps[16], tmp[16], r[16];
  softmax16(Lg + (size_t)tok * EDIM, pg);
  softmax16(Lsi + (size_t)tok * EDIM, ps);
  softmax16(Lsg + (size_t)tok * EDIM, tmp);
#pragma unroll
  for (int e = 0; e < 16; ++e) ps[e] += tmp[e];
  softmax16(Lsc + (size_t)tok * EDIM, tmp);
#pragma unroll
  for (int e = 0; e < 16; ++e) ps[e] += tmp[e];
  softmax16(Lsb + (size_t)tok * EDIM, tmp);
#pragma unroll
  for (int e = 0; e < 16; ++e) ps[e] += tmp[e];

#pragma unroll
  for (int e = 0; e < 16; ++e) {
    float s = ps[e] * 0.5f;
    r[e] = 0.7f * pg[e] + 0.3f * s;
  }

#pragma unroll
  for (int e = 0; e < 16; e += 4) {
    float4 o = {r[e], r[e + 1], r[e + 2], r[e + 3]};
    *(float4*)&router_probs[(size_t)tok * EDIM + e] = o;
  }

#pragma unroll
  for (int e = 0; e < 16; ++e) atomicAdd(&sm[e], r[e]);

  bool used[16];
#pragma unroll
  for (int e = 0; e < 16; ++e) used[e] = false;
  int idx[TOPK];
  float tp[TOPK];
  float tsum = 0.0f;
#pragma unroll
  for (int j = 0; j < TOPK; ++j) {
    float best = -1.0f;
    int bi = 0;
#pragma unroll
    for (int e = 0; e < 16; ++e) {
      bool take = (!used[e]) && (r[e] > best);
      best = take ? r[e] : best;
      bi = take ? e : bi;
    }
    used[bi] = true;
    idx[j] = bi;
    tp[j] = best;
    tsum += best;
  }
  float invt = 1.0f / tsum;
#pragma unroll
  for (int j = 0; j < TOPK; ++j) {
    size_t off = ((size_t)tok * EDIM + idx[j]) * CAPV;
    dispatch[off] = 1.0f;
    combine[off] = tp[j] * invt;
  }

  __syncthreads();
  if (tid < EDIM) atomicAdd(&mean_acc[tid], sm[tid]);
}

__global__ void aux_kernel(const float* __restrict__ mean_acc, float* __restrict__ out_aux) {
  if (threadIdx.x == 0 && blockIdx.x == 0) {
    float s = 0.0f;
    for (int e = 0; e < EDIM; ++e) {
      float m = mean_acc[e] * (1.0f / (float)NTOK);
      s += m * logf(m * (float)EDIM + 1e-9f);
    }
    *out_aux = s;
  }
}

// ---------------- launch ----------------
#define MBYTE (1ull << 20)

extern "C" void kernel_launch(void* const* d_in, const int* in_sizes, int n_in,
                              void* d_out, int out_size, void* d_ws, size_t ws_size,
                              hipStream_t stream) {
  const float* X    = (const float*)d_in[0];
  const float* IMG  = (const float*)d_in[1];
  const float* GEN  = (const float*)d_in[2];
  const float* g_w1 = (const float*)d_in[3];
  const float* g_b1 = (const float*)d_in[4];
  const float* g_w2 = (const float*)d_in[5];
  const float* g_b2 = (const float*)d_in[6];
  const float* m_w1 = (const float*)d_in[7];
  const float* m_b1 = (const float*)d_in[8];
  const float* m_w2 = (const float*)d_in[9];
  const float* m_b2 = (const float*)d_in[10];
  const float* si_w1 = (const float*)d_in[11];
  const float* si_b1 = (const float*)d_in[12];
  const float* si_w2 = (const float*)d_in[13];
  const float* si_b2 = (const float*)d_in[14];
  const float* sg_w1 = (const float*)d_in[15];
  const float* sg_b1 = (const float*)d_in[16];
  const float* sg_w2 = (const float*)d_in[17];
  const float* sg_b2 = (const float*)d_in[18];
  const float* sc_w1 = (const float*)d_in[19];
  const float* sc_b1 = (const float*)d_in[20];
  const float* sc_w2 = (const float*)d_in[21];
  const float* sc_b2 = (const float*)d_in[22];
  const float* sb_w1 = (const float*)d_in[23];
  const float* sb_b1 = (const float*)d_in[24];
  const float* sb_w2 = (const float*)d_in[25];
  const float* sb_b2 = (const float*)d_in[26];

  char* wsb = (char*)d_ws;
  // Flat region plan (~210 MB, all disjoint).
  __bf16* Xh    = (__bf16*)(wsb + 0 * MBYTE);
  __bf16* Xl    = (__bf16*)(wsb + 8 * MBYTE);
  __bf16* IMGh  = (__bf16*)(wsb + 16 * MBYTE);
  __bf16* IMGl  = (__bf16*)(wsb + 24 * MBYTE);
  __bf16* GENh  = (__bf16*)(wsb + 32 * MBYTE);
  __bf16* GENl  = (__bf16*)(wsb + 40 * MBYTE);
  __bf16* M2h   = (__bf16*)(wsb + 48 * MBYTE);   // m_w2 elementwise split
  __bf16* M2l   = (__bf16*)(wsb + 56 * MBYTE);
  __bf16* Wm1h  = (__bf16*)(wsb + 64 * MBYTE);
  __bf16* Wm1l  = (__bf16*)(wsb + 72 * MBYTE);
  __bf16* Wg1h  = (__bf16*)(wsb + 80 * MBYTE);
  __bf16* Wg1l  = (__bf16*)(wsb + 88 * MBYTE);
  __bf16* Wsch  = (__bf16*)(wsb + 96 * MBYTE);
  __bf16* Wscl  = (__bf16*)(wsb + 100 * MBYTE);
  __bf16* Wsbh  = (__bf16*)(wsb + 104 * MBYTE);
  __bf16* Wsbl  = (__bf16*)(wsb + 108 * MBYTE);
  __bf16* Wsih  = (__bf16*)(wsb + 112 * MBYTE);
  __bf16* Wsil  = (__bf16*)(wsb + 116 * MBYTE);
  __bf16* Wsgh  = (__bf16*)(wsb + 120 * MBYTE);
  __bf16* Wsgl  = (__bf16*)(wsb + 124 * MBYTE);
  __bf16* H1h   = (__bf16*)(wsb + 128 * MBYTE);
  __bf16* H1l   = (__bf16*)(wsb + 136 * MBYTE);
  __bf16* WPsch = (__bf16*)(wsb + 144 * MBYTE);  // (m_w2@sc_w1)^T split [1024][2048]
  __bf16* WPscl = (__bf16*)(wsb + 148 * MBYTE);
  __bf16* WPsbh = (__bf16*)(wsb + 152 * MBYTE);
  __bf16* WPsbl = (__bf16*)(wsb + 156 * MBYTE);
  float*  YG    = (float*)(wsb + 160 * MBYTE);
  float*  YSI   = (float*)(wsb + 176 * MBYTE);
  float*  YSG   = (float*)(wsb + 184 * MBYTE);
  float*  YSC   = (float*)(wsb + 192 * MBYTE);
  float*  YSB   = (float*)(wsb + 200 * MBYTE);
  float* L0 = (float*)(wsb + 208 * MBYTE);
  float* L1 = L0 + NTOK * EDIM;
  float* L2 = L1 + NTOK * EDIM;
  float* L3 = L2 + NTOK * EDIM;
  float* L4 = L3 + NTOK * EDIM;
  float* meanp = L4 + NTOK * EDIM;
  float* zbias = meanp + EDIM;         // 2048 zeros (bias for W' jobs)
  float* vsc = zbias + GK;
  float* vsb = vsc + HHALF;

  float* dispatch = (float*)d_out;
  float* combine = dispatch + (size_t)NTOK * EDIM * CAPV;
  float* rp = combine + (size_t)NTOK * EDIM * CAPV;
  float* aux = rp + (size_t)NTOK * EDIM;

  hipMemsetAsync(d_out, 0, (size_t)out_size * sizeof(float), stream);
  hipMemsetAsync(meanp, 0, (EDIM + GK) * sizeof(float), stream);

  dim3 blk(256);

  // 1) batched input splits (X, IMG, GEN, m_w2)
  {
    SJob a{X, Xh, Xl}, b{IMG, IMGh, IMGl}, c{GEN, GENh, GENl}, d{m_w2, M2h, M2l};
    split4<<<4 * SPLIT_BLKS, blk, 0, stream>>>(a, b, c, d);
  }

  // 2) batched weight transpose+split (6 weights)
  {
    TJobs t;
    t.j[0] = {m_w1, Wm1h, Wm1l, HDIM};
    t.j[1] = {g_w1, Wg1h, Wg1l, HDIM};
    t.j[2] = {sc_w1, Wsch, Wscl, HHALF};
    t.j[3] = {sb_w1, Wsbh, Wsbl, HHALF};
    t.j[4] = {si_w1, Wsih, Wsil, HHALF};
    t.j[5] = {sg_w1, Wsgh, Wsgl, HHALF};
    tsplit<<<dim3(64, 64, 6), blk, 0, stream>>>(t);
  }

  // 3) prebias vectors: v = m_b2 @ {sc,sb}_w1 + {sc,sb}_b1
  prebias<<<dim3(HHALF / 256, 2), blk, 0, stream>>>(m_b2, sc_w1, sc_b1, vsc,
                                                    sb_w1, sb_b1, vsb);

  // 4) GEMM stage A: 6 independent jobs, exactly 256 blocks
  {
    GJobsA g;
    g.j[0] = {Xh, Xl, Wm1h, Wm1l, m_b1, nullptr, H1h, H1l, 1, HDIM, 0};      // 64
    g.j[1] = {Xh, Xl, Wg1h, Wg1l, g_b1, YG, nullptr, nullptr, 1, HDIM, 64};  // 64
    g.j[2] = {IMGh, IMGl, Wsih, Wsil, si_b1, YSI, nullptr, nullptr, 1, HHALF, 128}; // 32
    g.j[3] = {GENh, GENl, Wsgh, Wsgl, sg_b1, YSG, nullptr, nullptr, 1, HHALF, 160}; // 32
    g.j[4] = {Wsch, Wscl, M2h, M2l, zbias, nullptr, WPsch, WPscl, 0, HDIM, 192};    // 32 (M=1024)
    g.j[5] = {Wsbh, Wsbl, M2h, M2l, zbias, nullptr, WPsbh, WPsbl, 0, HDIM, 224};    // 32 (M=1024)
    gemm_bigA<<<256, dim3(512), 0, stream>>>(g);
  }

  // 5) GEMM stage B': sc/sb hiddens = relu(H1 @ W' + v)
  {
    GJobs g;
    g.j[0] = {H1h, H1l, WPsch, WPscl, vsc, YSC, nullptr, nullptr, 1, HHALF, 0};
    g.j[1] = {H1h, H1l, WPsbh, WPsbl, vsb, YSB, nullptr, nullptr, 1, HHALF, 128};
    g.njobs = 2;
    gemm_split<<<256, blk, 0, stream>>>(g);
  }

  // 6) batched logits (all 5 routers)
  {
    LJobs l;
    l.j[0] = {YG, g_w2, g_b2, L0, HDIM};
    l.j[1] = {YSI, si_w2, si_b2, L1, HHALF};
    l.j[2] = {YSG, sg_w2, sg_b2, L2, HHALF};
    l.j[3] = {YSC, sc_w2, sc_b2, L3, HHALF};
    l.j[4] = {YSB, sb_w2, sb_b2, L4, HHALF};
    logits_kernel<<<5 * 256, blk, 0, stream>>>(l);
  }

  // 7) finalize + aux
  finalize_kernel<<<NTOK / 256, blk, 0, stream>>>(L0, L1, L2, L3, L4,
                                                  dispatch, combine, rp, meanp);
  aux_kernel<<<1, 64, 0, stream>>>(meanp, aux);
}

// Round 6
// 421.638 us; speedup vs baseline: 1.2270x; 1.2270x over previous
//
#include <hip/hip_runtime.h>
#include <math.h>
#include <stdint.h>

// Problem constants (B=2, S=1024, H=2048, E=16, K=4, CAP=768)
#define NTOK 2048
#define HDIM 2048
#define HHALF 1024
#define EDIM 16
#define CAPV 768
#define TOPK 4
#define GK 2048        // K is 2048 for every GEMM in this problem

typedef __bf16 bf16x8 __attribute__((ext_vector_type(8)));
typedef __bf16 bf16x4 __attribute__((ext_vector_type(4)));
typedef float f32x4 __attribute__((ext_vector_type(4)));

// =====================================================================
// Stage-A GEMM, 6-phase pipelined (T2+T3+T4+T5 port of the m201 schedule
// to the 3-term bf16 split).
// Tile 256x256, BK=32, 512 thr = 8 waves (2M x 4N), per-wave 128x64.
// LDS: 2 bufs x 4 arrays (Ah,Al,Bh,Bl) x [256][32]bf16 = 128 KB, 1 blk/CU.
// Per K-tile: 6 phases, one split-term x mh-half each (16 MFMAs/phase):
//   ph0: Ah0*Bh   reads Ah0(4)+Bh(4)   stage Ah(t+1)   gate-> vmcnt(4)
//   ph1: Ah0*Bl   reads Bl(4)          stage Bh(t+1)   gate-> vmcnt(4)
//   ph2: Al0*Bh   reads Al0(4)         stage Bl(t+1)
//   ph3: Ah1*Bh   reads Ah1(4)         stage Al(t+1)
//   ph4: Ah1*Bl   reads Al1(4)  (pre-read for ph5)
//   ph5: Al1*Bh   no reads                             gate-> vmcnt(4)
// Gates: vmcnt(4) keeps 4 loads in flight (never drains in main loop);
// every staged array has >=4 phases (~1000cyc) before its gate+barrier.
// All reads of a tile's data occur at least one barrier after the gate
// that covered that array (cross-wave safety of global_load_lds).
// =====================================================================

struct GJobA {
  const __bf16 *Ah, *Al, *Wh, *Wl;   // A [M][K] split; W^T [N][K] split
  const float* bias;
  float* Cf; __bf16 *Ch, *Cl;
  int relu, N, blk0;
};
struct GJobsA { GJobA j[6]; };

#define BKA 32
#define NTA 64   // 2048 / 32 K-tiles

#define BARR __builtin_amdgcn_s_barrier()
#define LGKM0 do { asm volatile("s_waitcnt lgkmcnt(0)" ::: "memory"); \
                   __builtin_amdgcn_sched_barrier(0); } while (0)
#define PRIO1 __builtin_amdgcn_s_setprio(1)
#define PRIO0 __builtin_amdgcn_s_setprio(0)

__global__ __launch_bounds__(512, 2) void gemm_phased(GJobsA P) {
  __shared__ __align__(16) __bf16 lds[2][4][256 * BKA];  // 128 KB

  const int tid = threadIdx.x;
  const int wid = tid >> 6, lane = tid & 63;
  const int lane15 = lane & 15, c0 = lane >> 4;

  // job select from flat block id
  const int bid = blockIdx.x;
  int ji = 0;
#pragma unroll
  for (int k = 1; k < 6; ++k)
    if (bid >= P.j[k].blk0) ji = k;
  const GJobA J = P.j[ji];
  const int local = bid - J.blk0;
  const int nbx = J.N >> 8;                 // 8 or 4 (power of two)
  const int bx = local & (nbx - 1);
  const int by = local / nbx;
  const int m0 = by * 256, n0 = bx * 256;

  const int wr = wid >> 2, wc = wid & 3;    // 2(M) x 4(N) waves -> 128x64 each

  // staging: per thread 2 chunks (16B) per array; source pre-swizzled
  int srow[2], soff[2];
#pragma unroll
  for (int h = 0; h < 2; ++h) {
    int s = tid + h * 512;
    int row = s >> 2;
    srow[h] = row;
    soff[h] = ((s & 3) ^ ((row >> 1) & 3)) * 8;
  }

  // fragment ds_read byte offsets (swizzled), constant across tiles
  int offB[4], offA[2][4];
#pragma unroll
  for (int ni = 0; ni < 4; ++ni) {
    int rb = wc * 64 + ni * 16 + lane15;
    offB[ni] = rb * 64 + ((c0 ^ ((rb >> 1) & 3)) << 4);
  }
#pragma unroll
  for (int mh = 0; mh < 2; ++mh)
#pragma unroll
    for (int i = 0; i < 4; ++i) {
      int ra = wr * 128 + mh * 64 + i * 16 + lane15;
      offA[mh][i] = ra * 64 + ((c0 ^ ((ra >> 1) & 3)) << 4);
    }

#define STAGE2(gptr, grow0, k1, larr)                                          \
  { _Pragma("unroll") for (int h = 0; h < 2; ++h) {                            \
      const __bf16* _src =                                                     \
          (gptr) + (size_t)((grow0) + srow[h]) * GK + (k1) + soff[h];          \
      __builtin_amdgcn_global_load_lds(                                        \
          (const __attribute__((address_space(1))) uint32_t*)_src,             \
          (__attribute__((address_space(3))) uint32_t*)((larr) +               \
              (wid * 64 + h * 512) * 8), 16, 0, 0); } }

#define DSR_A(dst, base, h)                                                    \
  { _Pragma("unroll") for (int i = 0; i < 4; ++i)                              \
      dst[i] = *(const bf16x8*)((base) + offA[h][i]); }
#define DSR_B(dst, base)                                                       \
  { _Pragma("unroll") for (int i = 0; i < 4; ++i)                              \
      dst[i] = *(const bf16x8*)((base) + offB[i]); }
#define MFMA16(af, bf, mh)                                                     \
  { _Pragma("unroll") for (int mi = 0; mi < 4; ++mi)                           \
    _Pragma("unroll") for (int ni = 0; ni < 4; ++ni)                           \
      acc[(mh) * 4 + mi][ni] = __builtin_amdgcn_mfma_f32_16x16x32_bf16(        \
          af[mi], bf[ni], acc[(mh) * 4 + mi][ni], 0, 0, 0); }

  f32x4 acc[8][4];
#pragma unroll
  for (int i = 0; i < 8; ++i)
#pragma unroll
    for (int j = 0; j < 4; ++j) acc[i][j] = (f32x4){0.f, 0.f, 0.f, 0.f};

  // prologue: stage all 4 arrays of tile 0, drain, barrier
  STAGE2(J.Ah, m0, 0, lds[0][0]);
  STAGE2(J.Wh, n0, 0, lds[0][2]);
  STAGE2(J.Wl, n0, 0, lds[0][3]);
  STAGE2(J.Al, m0, 0, lds[0][1]);
  asm volatile("s_waitcnt vmcnt(0)" ::: "memory");
  BARR;

  bf16x8 ah[4], al[4], bh[4], bl[4];

  for (int t = 0; t < NTA; ++t) {
    const int cur = t & 1, nxt = cur ^ 1;
    const bool hasNext = (t + 1 < NTA);
    const int k1 = (t + 1) * BKA;
    const char* cAh = (const char*)lds[cur][0];
    const char* cAl = (const char*)lds[cur][1];
    const char* cBh = (const char*)lds[cur][2];
    const char* cBl = (const char*)lds[cur][3];

    // ---- ph0: Ah0*Bh ----
    DSR_A(ah, cAh, 0);
    DSR_B(bh, cBh);
    if (hasNext) STAGE2(J.Ah, m0, k1, lds[nxt][0]);
    BARR; LGKM0;
    PRIO1; MFMA16(ah, bh, 0); PRIO0;
    if (hasNext) { asm volatile("s_waitcnt vmcnt(4)" ::: "memory"); }
    else         { asm volatile("s_waitcnt vmcnt(2)" ::: "memory"); }
    BARR;
    // ---- ph1: Ah0*Bl ----
    DSR_B(bl, cBl);
    if (hasNext) STAGE2(J.Wh, n0, k1, lds[nxt][2]);
    BARR; LGKM0;
    PRIO1; MFMA16(ah, bl, 0); PRIO0;
    if (hasNext) { asm volatile("s_waitcnt vmcnt(4)" ::: "memory"); }
    else         { asm volatile("s_waitcnt vmcnt(0)" ::: "memory"); }
    BARR;
    // ---- ph2: Al0*Bh ----
    DSR_A(al, cAl, 0);
    if (hasNext) STAGE2(J.Wl, n0, k1, lds[nxt][3]);
    BARR; LGKM0;
    PRIO1; MFMA16(al, bh, 0); PRIO0;
    BARR;
    // ---- ph3: Ah1*Bh ----
    DSR_A(ah, cAh, 1);
    if (hasNext) STAGE2(J.Al, m0, k1, lds[nxt][1]);
    BARR; LGKM0;
    PRIO1; MFMA16(ah, bh, 1); PRIO0;
    BARR;
    // ---- ph4: Ah1*Bl  (pre-read Al1 for ph5) ----
    DSR_A(al, cAl, 1);
    BARR; LGKM0;
    PRIO1; MFMA16(ah, bl, 1); PRIO0;
    BARR;
    // ---- ph5: Al1*Bh ----
    PRIO1; MFMA16(al, bh, 1); PRIO0;
    if (hasNext) { asm volatile("s_waitcnt vmcnt(4)" ::: "memory"); }
    BARR;
  }

  // epilogue: C/D layout col=lane&15, row=(lane>>4)*4+reg [m89]
#pragma unroll
  for (int mh = 0; mh < 2; ++mh)
#pragma unroll
    for (int mi = 0; mi < 4; ++mi)
#pragma unroll
      for (int ni = 0; ni < 4; ++ni) {
        int col = n0 + wc * 64 + ni * 16 + lane15;
        float bv = J.bias[col];
        f32x4 v = acc[mh * 4 + mi][ni];
#pragma unroll
        for (int j = 0; j < 4; ++j) {
          int row = m0 + wr * 128 + mh * 64 + mi * 16 + c0 * 4 + j;
          float x = v[j] + bv;
          if (J.relu) x = fmaxf(x, 0.0f);
          size_t o = (size_t)row * J.N + col;
          if (J.Cf) J.Cf[o] = x;
          if (J.Ch) {
            __bf16 hh = (__bf16)x;
            J.Ch[o] = hh;
            J.Cl[o] = (__bf16)(x - (float)hh);
          }
        }
      }
#undef STAGE2
#undef DSR_A
#undef DSR_B
#undef MFMA16
}

// =====================================================================
// Stage-B' GEMM: the proven 128x128 / BK=64 / 4-wave kernel.
// =====================================================================
#define BKT 64

struct GJob {
  const __bf16* Ah; const __bf16* Al;
  const __bf16* Wh; const __bf16* Wl;
  const float* bias;
  float* Cf;
  __bf16* Ch; __bf16* Cl;
  int relu; int N; int blk0;
};
struct GJobs { GJob j[4]; int njobs; };

__device__ __forceinline__ void stage_tile(const __bf16* __restrict__ g,
                                           int grow0, int k0,
                                           __bf16* lbase, int wid, int lane) {
  int r_in = lane >> 3;
  int swz_elems = ((lane & 7) ^ r_in) << 3;
#pragma unroll
  for (int i = 0; i < 4; ++i) {
    int row0 = wid * 32 + i * 8;
    const __bf16* src = g + (size_t)(grow0 + row0 + r_in) * GK + k0 + swz_elems;
    __builtin_amdgcn_global_load_lds(
        (const __attribute__((address_space(1))) uint32_t*)src,
        (__attribute__((address_space(3))) uint32_t*)(lbase + row0 * BKT),
        16, 0, 0);
  }
}

__global__ __launch_bounds__(256) void gemm_split(GJobs P) {
  __shared__ __align__(16) __bf16 lds[4 * 128 * BKT];
  __bf16* ldsAh = lds;
  __bf16* ldsAl = lds + 8192;
  __bf16* ldsBh = lds + 16384;
  __bf16* ldsBl = lds + 24576;
  const char* cAh = (const char*)ldsAh;
  const char* cAl = (const char*)ldsAl;
  const char* cBh = (const char*)ldsBh;
  const char* cBl = (const char*)ldsBl;

  const int bid = blockIdx.x;
  int ji = 0;
#pragma unroll
  for (int k = 1; k < 4; ++k)
    if (k < P.njobs && bid >= P.j[k].blk0) ji = k;
  const GJob J = P.j[ji];
  const int local = bid - J.blk0;
  const int nbx = J.N >> 7;
  const int bx = local & (nbx - 1);
  const int by = local / nbx;
  const int m0 = by * 128;
  const int n0 = bx * 128;

  const int tid = threadIdx.x;
  const int wid = tid >> 6;
  const int lane = tid & 63;
  const int lane15 = lane & 15;
  const int c0 = lane >> 4;
  const int wr = wid >> 1;
  const int wc = wid & 1;

  int offA[4][2], offB[4][2];
#pragma unroll
  for (int i = 0; i < 4; ++i) {
    int ra = wr * 64 + i * 16 + lane15;
    int rb = wc * 64 + i * 16 + lane15;
#pragma unroll
    for (int ks = 0; ks < 2; ++ks) {
      offA[i][ks] = ra * 128 + (((ks * 4 + c0) ^ (ra & 7)) << 4);
      offB[i][ks] = rb * 128 + (((ks * 4 + c0) ^ (rb & 7)) << 4);
    }
  }

  f32x4 acc[4][4];
#pragma unroll
  for (int i = 0; i < 4; ++i)
#pragma unroll
    for (int j = 0; j < 4; ++j) acc[i][j] = (f32x4){0.f, 0.f, 0.f, 0.f};

  for (int k0 = 0; k0 < GK; k0 += BKT) {
    stage_tile(J.Ah, m0, k0, ldsAh, wid, lane);
    stage_tile(J.Al, m0, k0, ldsAl, wid, lane);
    stage_tile(J.Wh, n0, k0, ldsBh, wid, lane);
    stage_tile(J.Wl, n0, k0, ldsBl, wid, lane);
    __syncthreads();
#pragma unroll
    for (int ks = 0; ks < 2; ++ks) {
      bf16x8 ah[4], al[4], bh[4], bl[4];
#pragma unroll
      for (int i = 0; i < 4; ++i) {
        ah[i] = *(const bf16x8*)(cAh + offA[i][ks]);
        al[i] = *(const bf16x8*)(cAl + offA[i][ks]);
        bh[i] = *(const bf16x8*)(cBh + offB[i][ks]);
        bl[i] = *(const bf16x8*)(cBl + offB[i][ks]);
      }
#pragma unroll
      for (int mi = 0; mi < 4; ++mi)
#pragma unroll
        for (int ni = 0; ni < 4; ++ni) {
          acc[mi][ni] = __builtin_amdgcn_mfma_f32_16x16x32_bf16(
              ah[mi], bh[ni], acc[mi][ni], 0, 0, 0);
          acc[mi][ni] = __builtin_amdgcn_mfma_f32_16x16x32_bf16(
              ah[mi], bl[ni], acc[mi][ni], 0, 0, 0);
          acc[mi][ni] = __builtin_amdgcn_mfma_f32_16x16x32_bf16(
              al[mi], bh[ni], acc[mi][ni], 0, 0, 0);
        }
    }
    __syncthreads();
  }

#pragma unroll
  for (int mi = 0; mi < 4; ++mi) {
#pragma unroll
    for (int ni = 0; ni < 4; ++ni) {
      int col = n0 + wc * 64 + ni * 16 + lane15;
      float bv = J.bias[col];
      f32x4 v = acc[mi][ni];
#pragma unroll
      for (int j = 0; j < 4; ++j) {
        int row = m0 + wr * 64 + mi * 16 + c0 * 4 + j;
        float x = v[j] + bv;
        if (J.relu) x = fmaxf(x, 0.0f);
        size_t o = (size_t)row * J.N + col;
        if (J.Cf) J.Cf[o] = x;
        if (J.Ch) {
          __bf16 hh = (__bf16)x;
          J.Ch[o] = hh;
          J.Cl[o] = (__bf16)(x - (float)hh);
        }
      }
    }
  }
}

// ---------------- fp32 -> (hi, lo) bf16 split, 4 inputs batched ----------------
struct SJob { const float* in; __bf16* h; __bf16* l; };
#define SPLIT_BLKS 4096
__global__ __launch_bounds__(256) void split4(SJob a, SJob b, SJob c, SJob d) {
  int job = blockIdx.x >> 12;
  SJob J = (job == 0) ? a : (job == 1) ? b : (job == 2) ? c : d;
  int i = (blockIdx.x & 4095) * 256 + threadIdx.x;
  float4 v = ((const float4*)J.in)[i];
  bf16x4 hv, lv;
  hv.x = (__bf16)v.x; lv.x = (__bf16)(v.x - (float)hv.x);
  hv.y = (__bf16)v.y; lv.y = (__bf16)(v.y - (float)hv.y);
  hv.z = (__bf16)v.z; lv.z = (__bf16)(v.z - (float)hv.z);
  hv.w = (__bf16)v.w; lv.w = (__bf16)(v.w - (float)hv.w);
  ((bf16x4*)J.h)[i] = hv;
  ((bf16x4*)J.l)[i] = lv;
}

// ------- W[2048][Nd] fp32 -> W^T hi/lo bf16 [Nd][2048], 6 weights batched -------
struct TJob { const float* W; __bf16* Th; __bf16* Tl; int Nd; };
struct TJobs { TJob j[6]; };
__global__ __launch_bounds__(256) void tsplit(TJobs P) {
  const TJob J = P.j[blockIdx.z];
  int n0 = blockIdx.x * 32;
  if (n0 >= J.Nd) return;
  int k0 = blockIdx.y * 32;
  __shared__ float t[32][33];
  int tx = threadIdx.x & 31, ty = threadIdx.x >> 5;
#pragma unroll
  for (int i = 0; i < 4; ++i) {
    int kk = ty + i * 8;
    t[kk][tx] = J.W[(size_t)(k0 + kk) * J.Nd + n0 + tx];
  }
  __syncthreads();
#pragma unroll
  for (int i = 0; i < 4; ++i) {
    int nn = ty + i * 8;
    float v = t[tx][nn];
    __bf16 hh = (__bf16)v;
    size_t o = (size_t)(n0 + nn) * GK + k0 + tx;
    J.Th[o] = hh;
    J.Tl[o] = (__bf16)(v - (float)hh);
  }
}

// -------- prebias: v[n] += sum_k b2[k]*W1[k][n] (+ b1[n]), k-split+atomic -------
__global__ __launch_bounds__(256) void prebias(
    const float* __restrict__ b2,
    const float* __restrict__ W1a, const float* __restrict__ b1a, float* va,
    const float* __restrict__ W1b, const float* __restrict__ b1b, float* vb) {
  const float* W1 = blockIdx.z ? W1b : W1a;
  const float* b1 = blockIdx.z ? b1b : b1a;
  float* v = blockIdx.z ? vb : va;
  int n = blockIdx.x * 256 + threadIdx.x;
  int k0 = blockIdx.y * 256;
  float acc = (blockIdx.y == 0) ? b1[n] : 0.0f;
#pragma unroll 8
  for (int k = 0; k < 256; ++k)
    acc = fmaf(b2[k0 + k], W1[(size_t)(k0 + k) * HHALF + n], acc);
  atomicAdd(&v[n], acc);
}

// ---------------- Skinny logits, 5 routers batched ----------------
struct LJob { const float* Y; const float* W2; const float* b2; float* L; int K; };
struct LJobs { LJob j[5]; };
__global__ __launch_bounds__(256) void logits_kernel(LJobs P) {
  const LJob J = P.j[blockIdx.x >> 8];
  const int blk = blockIdx.x & 255;
  const int tid = threadIdx.x;
  const int wid = tid >> 6, lane = tid & 63;
  const int e = lane & 15;
  const int kq = lane >> 4;
  const int tok0 = blk * 8 + wid * 2;
  const float* y0 = J.Y + (size_t)tok0 * J.K;
  const float* y1 = y0 + J.K;
  const int KQ = J.K >> 2;
  const int kbase = kq * KQ;
  float a0 = 0.f, a1 = 0.f;
#pragma unroll 8
  for (int k = 0; k < KQ; ++k) {
    int kk = kbase + k;
    float w = J.W2[(size_t)kk * EDIM + e];
    a0 = fmaf(y0[kk], w, a0);
    a1 = fmaf(y1[kk], w, a1);
  }
  a0 += __shfl_xor(a0, 16); a0 += __shfl_xor(a0, 32);
  a1 += __shfl_xor(a1, 16); a1 += __shfl_xor(a1, 32);
  if (lane < 16) {
    float b = J.b2[e];
    J.L[(size_t)tok0 * EDIM + e] = a0 + b;
    J.L[(size_t)(tok0 + 1) * EDIM + e] = a1 + b;
  }
}

// ---------------- Router finalize ----------------
__device__ __forceinline__ void softmax16(const float* __restrict__ L, float* __restrict__ p) {
  float v[16];
  *(float4*)&v[0]  = *(const float4*)&L[0];
  *(float4*)&v[4]  = *(const float4*)&L[4];
  *(float4*)&v[8]  = *(const float4*)&L[8];
  *(float4*)&v[12] = *(const float4*)&L[12];
  float m = v[0];
#pragma unroll
  for (int e = 1; e < 16; ++e) m = fmaxf(m, v[e]);
  float s = 0.0f;
#pragma unroll
  for (int e = 0; e < 16; ++e) { v[e] = expf(v[e] - m); s += v[e]; }
  float inv = 1.0f / s;
#pragma unroll
  for (int e = 0; e < 16; ++e) p[e] = v[e] * inv;
}

__global__ __launch_bounds__(256) void finalize_kernel(
    const float* __restrict__ Lg, const float* __restrict__ Lsi,
    const float* __restrict__ Lsg, const float* __restrict__ Lsc,
    const float* __restrict__ Lsb,
    float* __restrict__ dispatch, float* __restrict__ combine,
    float* __restrict__ router_probs, float* __restrict__ mean_acc) {
  __shared__ float sm[EDIM];
  int tid = threadIdx.x;
  if (tid < EDIM) sm[tid] = 0.0f;
  __syncthreads();

  int tok = blockIdx.x * 256 + tid;
  float pg[16], ps[16], tmp[16], r[16];
  softmax16(Lg + (size_t)tok * EDIM, pg);
  softmax16(Lsi + (size_t)tok * EDIM, ps);
  softmax16(Lsg + (size_t)tok * EDIM, tmp);
#pragma unroll
  for (int e = 0; e < 16; ++e) ps[e] += tmp[e];
  softmax16(Lsc + (size_t)tok * EDIM, tmp);
#pragma unroll
  for (int e = 0; e < 16; ++e) ps[e] += tmp[e];
  softmax16(Lsb + (size_t)tok * EDIM, tmp);
#pragma unroll
  for (int e = 0; e < 16; ++e) ps[e] += tmp[e];

#pragma unroll
  for (int e = 0; e < 16; ++e) {
    float s = ps[e] * 0.5f;
    r[e] = 0.7f * pg[e] + 0.3f * s;
  }

#pragma unroll
  for (int e = 0; e < 16; e += 4) {
    float4 o = {r[e], r[e + 1], r[e + 2], r[e + 3]};
    *(float4*)&router_probs[(size_t)tok * EDIM + e] = o;
  }

#pragma unroll
  for (int e = 0; e < 16; ++e) atomicAdd(&sm[e], r[e]);

  bool used[16];
#pragma unroll
  for (int e = 0; e < 16; ++e) used[e] = false;
  int idx[TOPK];
  float tp[TOPK];
  float tsum = 0.0f;
#pragma unroll
  for (int j = 0; j < TOPK; ++j) {
    float best = -1.0f;
    int bi = 0;
#pragma unroll
    for (int e = 0; e < 16; ++e) {
      bool take = (!used[e]) && (r[e] > best);
      best = take ? r[e] : best;
      bi = take ? e : bi;
    }
    used[bi] = true;
    idx[j] = bi;
    tp[j] = best;
    tsum += best;
  }
  float invt = 1.0f / tsum;
#pragma unroll
  for (int j = 0; j < TOPK; ++j) {
    size_t off = ((size_t)tok * EDIM + idx[j]) * CAPV;
    dispatch[off] = 1.0f;
    combine[off] = tp[j] * invt;
  }

  __syncthreads();
  if (tid < EDIM) atomicAdd(&mean_acc[tid], sm[tid]);
}

__global__ void aux_kernel(const float* __restrict__ mean_acc, float* __restrict__ out_aux) {
  if (threadIdx.x == 0 && blockIdx.x == 0) {
    float s = 0.0f;
    for (int e = 0; e < EDIM; ++e) {
      float m = mean_acc[e] * (1.0f / (float)NTOK);
      s += m * logf(m * (float)EDIM + 1e-9f);
    }
    *out_aux = s;
  }
}

// ---------------- launch ----------------
#define MBYTE (1ull << 20)

extern "C" void kernel_launch(void* const* d_in, const int* in_sizes, int n_in,
                              void* d_out, int out_size, void* d_ws, size_t ws_size,
                              hipStream_t stream) {
  const float* X    = (const float*)d_in[0];
  const float* IMG  = (const float*)d_in[1];
  const float* GEN  = (const float*)d_in[2];
  const float* g_w1 = (const float*)d_in[3];
  const float* g_b1 = (const float*)d_in[4];
  const float* g_w2 = (const float*)d_in[5];
  const float* g_b2 = (const float*)d_in[6];
  const float* m_w1 = (const float*)d_in[7];
  const float* m_b1 = (const float*)d_in[8];
  const float* m_w2 = (const float*)d_in[9];
  const float* m_b2 = (const float*)d_in[10];
  const float* si_w1 = (const float*)d_in[11];
  const float* si_b1 = (const float*)d_in[12];
  const float* si_w2 = (const float*)d_in[13];
  const float* si_b2 = (const float*)d_in[14];
  const float* sg_w1 = (const float*)d_in[15];
  const float* sg_b1 = (const float*)d_in[16];
  const float* sg_w2 = (const float*)d_in[17];
  const float* sg_b2 = (const float*)d_in[18];
  const float* sc_w1 = (const float*)d_in[19];
  const float* sc_b1 = (const float*)d_in[20];
  const float* sc_w2 = (const float*)d_in[21];
  const float* sc_b2 = (const float*)d_in[22];
  const float* sb_w1 = (const float*)d_in[23];
  const float* sb_b1 = (const float*)d_in[24];
  const float* sb_w2 = (const float*)d_in[25];
  const float* sb_b2 = (const float*)d_in[26];

  char* wsb = (char*)d_ws;
  __bf16* Xh    = (__bf16*)(wsb + 0 * MBYTE);
  __bf16* Xl    = (__bf16*)(wsb + 8 * MBYTE);
  __bf16* IMGh  = (__bf16*)(wsb + 16 * MBYTE);
  __bf16* IMGl  = (__bf16*)(wsb + 24 * MBYTE);
  __bf16* GENh  = (__bf16*)(wsb + 32 * MBYTE);
  __bf16* GENl  = (__bf16*)(wsb + 40 * MBYTE);
  __bf16* M2h   = (__bf16*)(wsb + 48 * MBYTE);   // m_w2 elementwise split
  __bf16* M2l   = (__bf16*)(wsb + 56 * MBYTE);
  __bf16* Wm1h  = (__bf16*)(wsb + 64 * MBYTE);
  __bf16* Wm1l  = (__bf16*)(wsb + 72 * MBYTE);
  __bf16* Wg1h  = (__bf16*)(wsb + 80 * MBYTE);
  __bf16* Wg1l  = (__bf16*)(wsb + 88 * MBYTE);
  __bf16* Wsch  = (__bf16*)(wsb + 96 * MBYTE);
  __bf16* Wscl  = (__bf16*)(wsb + 100 * MBYTE);
  __bf16* Wsbh  = (__bf16*)(wsb + 104 * MBYTE);
  __bf16* Wsbl  = (__bf16*)(wsb + 108 * MBYTE);
  __bf16* Wsih  = (__bf16*)(wsb + 112 * MBYTE);
  __bf16* Wsil  = (__bf16*)(wsb + 116 * MBYTE);
  __bf16* Wsgh  = (__bf16*)(wsb + 120 * MBYTE);
  __bf16* Wsgl  = (__bf16*)(wsb + 124 * MBYTE);
  __bf16* H1h   = (__bf16*)(wsb + 128 * MBYTE);
  __bf16* H1l   = (__bf16*)(wsb + 136 * MBYTE);
  __bf16* WPsch = (__bf16*)(wsb + 144 * MBYTE);  // (m_w2@sc_w1)^T split [1024][2048]
  __bf16* WPscl = (__bf16*)(wsb + 148 * MBYTE);
  __bf16* WPsbh = (__bf16*)(wsb + 152 * MBYTE);
  __bf16* WPsbl = (__bf16*)(wsb + 156 * MBYTE);
  float*  YG    = (float*)(wsb + 160 * MBYTE);
  float*  YSI   = (float*)(wsb + 176 * MBYTE);
  float*  YSG   = (float*)(wsb + 184 * MBYTE);
  float*  YSC   = (float*)(wsb + 192 * MBYTE);
  float*  YSB   = (float*)(wsb + 200 * MBYTE);
  float* L0 = (float*)(wsb + 208 * MBYTE);
  float* L1 = L0 + NTOK * EDIM;
  float* L2 = L1 + NTOK * EDIM;
  float* L3 = L2 + NTOK * EDIM;
  float* L4 = L3 + NTOK * EDIM;
  float* meanp = L4 + NTOK * EDIM;
  float* zbias = meanp + EDIM;         // 2048 zeros (bias for W' jobs)
  float* vsc = zbias + GK;
  float* vsb = vsc + HHALF;

  float* dispatch = (float*)d_out;
  float* combine = dispatch + (size_t)NTOK * EDIM * CAPV;
  float* rp = combine + (size_t)NTOK * EDIM * CAPV;
  float* aux = rp + (size_t)NTOK * EDIM;

  hipMemsetAsync(d_out, 0, (size_t)out_size * sizeof(float), stream);
  // zero meanp + zbias + vsc + vsb (contiguous)
  hipMemsetAsync(meanp, 0, (EDIM + GK + 2 * HHALF) * sizeof(float), stream);

  dim3 blk(256);

  // 1) batched input splits (X, IMG, GEN, m_w2)
  {
    SJob a{X, Xh, Xl}, b{IMG, IMGh, IMGl}, c{GEN, GENh, GENl}, d{m_w2, M2h, M2l};
    split4<<<4 * SPLIT_BLKS, blk, 0, stream>>>(a, b, c, d);
  }

  // 2) batched weight transpose+split (6 weights)
  {
    TJobs t;
    t.j[0] = {m_w1, Wm1h, Wm1l, HDIM};
    t.j[1] = {g_w1, Wg1h, Wg1l, HDIM};
    t.j[2] = {sc_w1, Wsch, Wscl, HHALF};
    t.j[3] = {sb_w1, Wsbh, Wsbl, HHALF};
    t.j[4] = {si_w1, Wsih, Wsil, HHALF};
    t.j[5] = {sg_w1, Wsgh, Wsgl, HHALF};
    tsplit<<<dim3(64, 64, 6), blk, 0, stream>>>(t);
  }

  // 3) prebias vectors: v = m_b2 @ {sc,sb}_w1 + {sc,sb}_b1  (k-split + atomics)
  prebias<<<dim3(HHALF / 256, 8, 2), blk, 0, stream>>>(m_b2, sc_w1, sc_b1, vsc,
                                                       sb_w1, sb_b1, vsb);

  // 4) GEMM stage A: 6 independent jobs, exactly 256 blocks (6-phase kernel)
  {
    GJobsA g;
    g.j[0] = {Xh, Xl, Wm1h, Wm1l, m_b1, nullptr, H1h, H1l, 1, HDIM, 0};      // 64
    g.j[1] = {Xh, Xl, Wg1h, Wg1l, g_b1, YG, nullptr, nullptr, 1, HDIM, 64};  // 64
    g.j[2] = {IMGh, IMGl, Wsih, Wsil, si_b1, YSI, nullptr, nullptr, 1, HHALF, 128}; // 32
    g.j[3] = {GENh, GENl, Wsgh, Wsgl, sg_b1, YSG, nullptr, nullptr, 1, HHALF, 160}; // 32
    g.j[4] = {Wsch, Wscl, M2h, M2l, zbias, nullptr, WPsch, WPscl, 0, HDIM, 192};    // 32 (M=1024)
    g.j[5] = {Wsbh, Wsbl, M2h, M2l, zbias, nullptr, WPsbh, WPsbl, 0, HDIM, 224};    // 32 (M=1024)
    gemm_phased<<<256, dim3(512), 0, stream>>>(g);
  }

  // 5) GEMM stage B': sc/sb hiddens = relu(H1 @ W' + v)
  {
    GJobs g;
    g.j[0] = {H1h, H1l, WPsch, WPscl, vsc, YSC, nullptr, nullptr, 1, HHALF, 0};
    g.j[1] = {H1h, H1l, WPsbh, WPsbl, vsb, YSB, nullptr, nullptr, 1, HHALF, 128};
    g.njobs = 2;
    gemm_split<<<256, blk, 0, stream>>>(g);
  }

  // 6) batched logits (all 5 routers)
  {
    LJobs l;
    l.j[0] = {YG, g_w2, g_b2, L0, HDIM};
    l.j[1] = {YSI, si_w2, si_b2, L1, HHALF};
    l.j[2] = {YSG, sg_w2, sg_b2, L2, HHALF};
    l.j[3] = {YSC, sc_w2, sc_b2, L3, HHALF};
    l.j[4] = {YSB, sb_w2, sb_b2, L4, HHALF};
    logits_kernel<<<5 * 256, blk, 0, stream>>>(l);
  }

  // 7) finalize + aux
  finalize_kernel<<<NTOK / 256, blk, 0, stream>>>(L0, L1, L2, L3, L4,
                                                  dispatch, combine, rp, meanp);
  aux_kernel<<<1, 64, 0, stream>>>(meanp, aux);
}

// Round 7
// 405.813 us; speedup vs baseline: 1.2749x; 1.0390x over previous
//
#include <hip/hip_runtime.h>
#include <math.h>
#include <stdint.h>

// Problem constants (B=2, S=1024, H=2048, E=16, K=4, CAP=768)
#define NTOK 2048
#define HDIM 2048
#define HHALF 1024
#define EDIM 16
#define CAPV 768
#define TOPK 4
#define GK 2048        // K is 2048 for every GEMM in this problem

typedef __bf16 bf16x8 __attribute__((ext_vector_type(8)));
typedef __bf16 bf16x4 __attribute__((ext_vector_type(4)));
typedef float f32x4 __attribute__((ext_vector_type(4)));

// =====================================================================
// Stage-A GEMM, 3-phase pipelined (T2+T3+T4+T5; 32 MFMA per phase).
// Tile 256x256, BK=32, 512 thr = 8 waves (2M x 4N), per-wave 128x64.
// LDS: 2 bufs x 4 arrays (Ah,Al,Bh,Bl) x [256][32]bf16 = 128 KB.
// Per K-tile (steady state; per-thread load FIFO in brackets):
//  enter tile t: outstanding [Al(t)x2]
//  ph0: read Ah0,Bh,Bl | stage Ah(t+1)      -> [Al2,Ah2]
//       barr; lgkm0; 32 MFMA (Ah0*Bh, Ah0*Bl); vmcnt(2)=Al landed; barr
//  ph1: read Al0,Ah1   | stage Bh,Bl,Al(t+1)-> [Ah2,Bh2,Bl2,Al2]
//       barr; lgkm0; 32 MFMA (Al0*Bh, Ah1*Bh); barr
//  ph2: read Al1
//       barr; lgkm0; 32 MFMA (Ah1*Bl, Al1*Bh); vmcnt(2)=Ah,Bh,Bl landed; barr
//  -> exit with [Al(t+1)x2].  6 barriers/tile (was 12), never vmcnt(0).
// Every gate precedes a barrier; all reads of staged data occur after
// that barrier (per-wave vmcnt + barrier = chip-wide visibility).
// =====================================================================

struct GJobA {
  const __bf16 *Ah, *Al, *Wh, *Wl;   // A [M][K] split; W^T [N][K] split
  const float* bias;
  float* Cf; __bf16 *Ch, *Cl;
  int relu, N, blk0;
};
struct GJobsA { GJobA j[6]; };

#define BKA 32
#define NTA 64   // 2048 / 32 K-tiles

#define BARR __builtin_amdgcn_s_barrier()
#define LGKM0 do { asm volatile("s_waitcnt lgkmcnt(0)" ::: "memory"); \
                   __builtin_amdgcn_sched_barrier(0); } while (0)
#define PRIO1 __builtin_amdgcn_s_setprio(1)
#define PRIO0 __builtin_amdgcn_s_setprio(0)

__global__ __launch_bounds__(512, 2) void gemm_phased(GJobsA P) {
  __shared__ __align__(16) __bf16 lds[2][4][256 * BKA];  // 128 KB

  const int tid = threadIdx.x;
  const int wid = tid >> 6, lane = tid & 63;
  const int lane15 = lane & 15, c0 = lane >> 4;

  // job select from flat block id
  const int bid = blockIdx.x;
  int ji = 0;
#pragma unroll
  for (int k = 1; k < 6; ++k)
    if (bid >= P.j[k].blk0) ji = k;
  const GJobA J = P.j[ji];
  const int local = bid - J.blk0;
  const int nbx = J.N >> 8;                 // 8 or 4 (power of two)
  const int bx = local & (nbx - 1);
  const int by = local / nbx;
  const int m0 = by * 256, n0 = bx * 256;

  const int wr = wid >> 2, wc = wid & 3;    // 2(M) x 4(N) waves -> 128x64 each

  // staging: per thread 2 chunks (16B) per array; source pre-swizzled
  int srow[2], soff[2];
#pragma unroll
  for (int h = 0; h < 2; ++h) {
    int s = tid + h * 512;
    int row = s >> 2;
    srow[h] = row;
    soff[h] = ((s & 3) ^ ((row >> 1) & 3)) * 8;
  }

  // fragment ds_read byte offsets (swizzled), constant across tiles
  int offB[4], offA[2][4];
#pragma unroll
  for (int ni = 0; ni < 4; ++ni) {
    int rb = wc * 64 + ni * 16 + lane15;
    offB[ni] = rb * 64 + ((c0 ^ ((rb >> 1) & 3)) << 4);
  }
#pragma unroll
  for (int mh = 0; mh < 2; ++mh)
#pragma unroll
    for (int i = 0; i < 4; ++i) {
      int ra = wr * 128 + mh * 64 + i * 16 + lane15;
      offA[mh][i] = ra * 64 + ((c0 ^ ((ra >> 1) & 3)) << 4);
    }

#define STAGE2(gptr, grow0, k1, larr)                                          \
  { _Pragma("unroll") for (int h = 0; h < 2; ++h) {                            \
      const __bf16* _src =                                                     \
          (gptr) + (size_t)((grow0) + srow[h]) * GK + (k1) + soff[h];          \
      __builtin_amdgcn_global_load_lds(                                        \
          (const __attribute__((address_space(1))) uint32_t*)_src,             \
          (__attribute__((address_space(3))) uint32_t*)((larr) +               \
              (wid * 64 + h * 512) * 8), 16, 0, 0); } }

#define DSR_A(dst, base, h)                                                    \
  { _Pragma("unroll") for (int i = 0; i < 4; ++i)                              \
      dst[i] = *(const bf16x8*)((base) + offA[h][i]); }
#define DSR_B(dst, base)                                                       \
  { _Pragma("unroll") for (int i = 0; i < 4; ++i)                              \
      dst[i] = *(const bf16x8*)((base) + offB[i]); }
#define MFMA16(af, bf, mh)                                                     \
  { _Pragma("unroll") for (int mi = 0; mi < 4; ++mi)                           \
    _Pragma("unroll") for (int ni = 0; ni < 4; ++ni)                           \
      acc[(mh) * 4 + mi][ni] = __builtin_amdgcn_mfma_f32_16x16x32_bf16(        \
          af[mi], bf[ni], acc[(mh) * 4 + mi][ni], 0, 0, 0); }

  f32x4 acc[8][4];
#pragma unroll
  for (int i = 0; i < 8; ++i)
#pragma unroll
    for (int j = 0; j < 4; ++j) acc[i][j] = (f32x4){0.f, 0.f, 0.f, 0.f};

  // prologue: stage tile 0 in FIFO order Ah,Bh,Bl,Al; gate to Al-in-flight
  STAGE2(J.Ah, m0, 0, lds[0][0]);
  STAGE2(J.Wh, n0, 0, lds[0][2]);
  STAGE2(J.Wl, n0, 0, lds[0][3]);
  STAGE2(J.Al, m0, 0, lds[0][1]);
  asm volatile("s_waitcnt vmcnt(2)" ::: "memory");   // Ah,Bh,Bl landed
  BARR;

  bf16x8 ah[4], al[4], bh[4], bl[4];

  for (int t = 0; t < NTA; ++t) {
    const int cur = t & 1, nxt = cur ^ 1;
    const bool hasNext = (t + 1 < NTA);
    const int k1 = (t + 1) * BKA;
    const char* cAh = (const char*)lds[cur][0];
    const char* cAl = (const char*)lds[cur][1];
    const char* cBh = (const char*)lds[cur][2];
    const char* cBl = (const char*)lds[cur][3];

    // ---- ph0: Ah0*Bh + Ah0*Bl ----
    DSR_A(ah, cAh, 0);
    DSR_B(bh, cBh);
    DSR_B(bl, cBl);
    if (hasNext) STAGE2(J.Ah, m0, k1, lds[nxt][0]);
    BARR; LGKM0;
    PRIO1; MFMA16(ah, bh, 0); MFMA16(ah, bl, 0); PRIO0;
    if (hasNext) { asm volatile("s_waitcnt vmcnt(2)" ::: "memory"); }
    else         { asm volatile("s_waitcnt vmcnt(0)" ::: "memory"); }
    BARR;
    // ---- ph1: Al0*Bh + Ah1*Bh ----
    DSR_A(al, cAl, 0);
    DSR_A(ah, cAh, 1);
    if (hasNext) {
      STAGE2(J.Wh, n0, k1, lds[nxt][2]);
      STAGE2(J.Wl, n0, k1, lds[nxt][3]);
      STAGE2(J.Al, m0, k1, lds[nxt][1]);
    }
    BARR; LGKM0;
    PRIO1; MFMA16(al, bh, 0); MFMA16(ah, bh, 1); PRIO0;
    BARR;
    // ---- ph2: Ah1*Bl + Al1*Bh ----
    DSR_A(al, cAl, 1);
    BARR; LGKM0;
    PRIO1; MFMA16(ah, bl, 1); MFMA16(al, bh, 1); PRIO0;
    if (hasNext) { asm volatile("s_waitcnt vmcnt(2)" ::: "memory"); }
    BARR;
  }

  // epilogue: C/D layout col=lane&15, row=(lane>>4)*4+reg [m89]
#pragma unroll
  for (int mh = 0; mh < 2; ++mh)
#pragma unroll
    for (int mi = 0; mi < 4; ++mi)
#pragma unroll
      for (int ni = 0; ni < 4; ++ni) {
        int col = n0 + wc * 64 + ni * 16 + lane15;
        float bv = J.bias[col];
        f32x4 v = acc[mh * 4 + mi][ni];
#pragma unroll
        for (int j = 0; j < 4; ++j) {
          int row = m0 + wr * 128 + mh * 64 + mi * 16 + c0 * 4 + j;
          float x = v[j] + bv;
          if (J.relu) x = fmaxf(x, 0.0f);
          size_t o = (size_t)row * J.N + col;
          if (J.Cf) J.Cf[o] = x;
          if (J.Ch) {
            __bf16 hh = (__bf16)x;
            J.Ch[o] = hh;
            J.Cl[o] = (__bf16)(x - (float)hh);
          }
        }
      }
#undef STAGE2
#undef DSR_A
#undef DSR_B
#undef MFMA16
}

// =====================================================================
// Stage-B' GEMM: proven 128x128 / BK=64 / 4-wave kernel, + kLen for
// split-K (pointers pre-offset by the host; partials, relu deferred).
// =====================================================================
#define BKT 64

struct GJob {
  const __bf16* Ah; const __bf16* Al;
  const __bf16* Wh; const __bf16* Wl;
  const float* bias;
  float* Cf;
  __bf16* Ch; __bf16* Cl;
  int relu; int N; int blk0; int kLen;
};
struct GJobs { GJob j[4]; int njobs; };

__device__ __forceinline__ void stage_tile(const __bf16* __restrict__ g,
                                           int grow0, int k0,
                                           __bf16* lbase, int wid, int lane) {
  int r_in = lane >> 3;
  int swz_elems = ((lane & 7) ^ r_in) << 3;
#pragma unroll
  for (int i = 0; i < 4; ++i) {
    int row0 = wid * 32 + i * 8;
    const __bf16* src = g + (size_t)(grow0 + row0 + r_in) * GK + k0 + swz_elems;
    __builtin_amdgcn_global_load_lds(
        (const __attribute__((address_space(1))) uint32_t*)src,
        (__attribute__((address_space(3))) uint32_t*)(lbase + row0 * BKT),
        16, 0, 0);
  }
}

__global__ __launch_bounds__(256) void gemm_split(GJobs P) {
  __shared__ __align__(16) __bf16 lds[4 * 128 * BKT];
  __bf16* ldsAh = lds;
  __bf16* ldsAl = lds + 8192;
  __bf16* ldsBh = lds + 16384;
  __bf16* ldsBl = lds + 24576;
  const char* cAh = (const char*)ldsAh;
  const char* cAl = (const char*)ldsAl;
  const char* cBh = (const char*)ldsBh;
  const char* cBl = (const char*)ldsBl;

  const int bid = blockIdx.x;
  int ji = 0;
#pragma unroll
  for (int k = 1; k < 4; ++k)
    if (k < P.njobs && bid >= P.j[k].blk0) ji = k;
  const GJob J = P.j[ji];
  const int local = bid - J.blk0;
  const int nbx = J.N >> 7;
  const int bx = local & (nbx - 1);
  const int by = local / nbx;
  const int m0 = by * 128;
  const int n0 = bx * 128;

  const int tid = threadIdx.x;
  const int wid = tid >> 6;
  const int lane = tid & 63;
  const int lane15 = lane & 15;
  const int c0 = lane >> 4;
  const int wr = wid >> 1;
  const int wc = wid & 1;

  int offA[4][2], offB[4][2];
#pragma unroll
  for (int i = 0; i < 4; ++i) {
    int ra = wr * 64 + i * 16 + lane15;
    int rb = wc * 64 + i * 16 + lane15;
#pragma unroll
    for (int ks = 0; ks < 2; ++ks) {
      offA[i][ks] = ra * 128 + (((ks * 4 + c0) ^ (ra & 7)) << 4);
      offB[i][ks] = rb * 128 + (((ks * 4 + c0) ^ (rb & 7)) << 4);
    }
  }

  f32x4 acc[4][4];
#pragma unroll
  for (int i = 0; i < 4; ++i)
#pragma unroll
    for (int j = 0; j < 4; ++j) acc[i][j] = (f32x4){0.f, 0.f, 0.f, 0.f};

  for (int k0 = 0; k0 < J.kLen; k0 += BKT) {
    stage_tile(J.Ah, m0, k0, ldsAh, wid, lane);
    stage_tile(J.Al, m0, k0, ldsAl, wid, lane);
    stage_tile(J.Wh, n0, k0, ldsBh, wid, lane);
    stage_tile(J.Wl, n0, k0, ldsBl, wid, lane);
    __syncthreads();
#pragma unroll
    for (int ks = 0; ks < 2; ++ks) {
      bf16x8 ah[4], al[4], bh[4], bl[4];
#pragma unroll
      for (int i = 0; i < 4; ++i) {
        ah[i] = *(const bf16x8*)(cAh + offA[i][ks]);
        al[i] = *(const bf16x8*)(cAl + offA[i][ks]);
        bh[i] = *(const bf16x8*)(cBh + offB[i][ks]);
        bl[i] = *(const bf16x8*)(cBl + offB[i][ks]);
      }
#pragma unroll
      for (int mi = 0; mi < 4; ++mi)
#pragma unroll
        for (int ni = 0; ni < 4; ++ni) {
          acc[mi][ni] = __builtin_amdgcn_mfma_f32_16x16x32_bf16(
              ah[mi], bh[ni], acc[mi][ni], 0, 0, 0);
          acc[mi][ni] = __builtin_amdgcn_mfma_f32_16x16x32_bf16(
              ah[mi], bl[ni], acc[mi][ni], 0, 0, 0);
          acc[mi][ni] = __builtin_amdgcn_mfma_f32_16x16x32_bf16(
              al[mi], bh[ni], acc[mi][ni], 0, 0, 0);
        }
    }
    __syncthreads();
  }

#pragma unroll
  for (int mi = 0; mi < 4; ++mi) {
#pragma unroll
    for (int ni = 0; ni < 4; ++ni) {
      int col = n0 + wc * 64 + ni * 16 + lane15;
      float bv = J.bias[col];
      f32x4 v = acc[mi][ni];
#pragma unroll
      for (int j = 0; j < 4; ++j) {
        int row = m0 + wr * 64 + mi * 16 + c0 * 4 + j;
        float x = v[j] + bv;
        if (J.relu) x = fmaxf(x, 0.0f);
        size_t o = (size_t)row * J.N + col;
        if (J.Cf) J.Cf[o] = x;
        if (J.Ch) {
          __bf16 hh = (__bf16)x;
          J.Ch[o] = hh;
          J.Cl[o] = (__bf16)(x - (float)hh);
        }
      }
    }
  }
}

// =====================================================================
// prep: fused preprocessing — 4 elementwise splits + 6 transpose-splits
// + 2 prebias reductions, one dispatch via flat block-range job table.
// blocks [0,16384): split; [16384,32768): tsplit; [32768,32832): prebias.
// =====================================================================
struct SJob { const float* in; __bf16* h; __bf16* l; };
struct TJob { const float* W; __bf16* Th; __bf16* Tl; int Nd; };
struct PrepArgs {
  SJob s[4];
  TJob t[6];
  const float* pb2;
  const float* pW1a; const float* pb1a; float* pva;
  const float* pW1b; const float* pb1b; float* pvb;
};

__global__ __launch_bounds__(256) void prep(PrepArgs P) {
  __shared__ float tbuf[32][33];
  const int bid = blockIdx.x;
  const int tid = threadIdx.x;
  if (bid < 16384) {
    // elementwise fp32 -> hi/lo bf16 split
    SJob J = P.s[bid >> 12];
    int i = (bid & 4095) * 256 + tid;
    float4 v = ((const float4*)J.in)[i];
    bf16x4 hv, lv;
    hv.x = (__bf16)v.x; lv.x = (__bf16)(v.x - (float)hv.x);
    hv.y = (__bf16)v.y; lv.y = (__bf16)(v.y - (float)hv.y);
    hv.z = (__bf16)v.z; lv.z = (__bf16)(v.z - (float)hv.z);
    hv.w = (__bf16)v.w; lv.w = (__bf16)(v.w - (float)hv.w);
    ((bf16x4*)J.h)[i] = hv;
    ((bf16x4*)J.l)[i] = lv;
  } else if (bid < 32768) {
    // W[2048][Nd] -> W^T hi/lo [Nd][2048]
    int local = bid - 16384;
    int ji, ln;
    if (local < 4096)      { ji = 0; ln = local; }
    else if (local < 8192) { ji = 1; ln = local - 4096; }
    else { ji = 2 + ((local - 8192) >> 11); ln = (local - 8192) & 2047; }
    TJob J = P.t[ji];
    int full = (J.Nd == HDIM);
    int n0 = (full ? (ln & 63) : (ln & 31)) * 32;
    int k0 = (full ? (ln >> 6) : (ln >> 5)) * 32;
    int tx = tid & 31, ty = tid >> 5;
#pragma unroll
    for (int i = 0; i < 4; ++i) {
      int kk = ty + i * 8;
      tbuf[kk][tx] = J.W[(size_t)(k0 + kk) * J.Nd + n0 + tx];
    }
    __syncthreads();
#pragma unroll
    for (int i = 0; i < 4; ++i) {
      int nn = ty + i * 8;
      float v = tbuf[tx][nn];
      __bf16 hh = (__bf16)v;
      size_t o = (size_t)(n0 + nn) * GK + k0 + tx;
      J.Th[o] = hh;
      J.Tl[o] = (__bf16)(v - (float)hh);
    }
  } else {
    // prebias: v[n] += sum_k b2[k]*W1[k][n] (+ b1[n] on first k-block)
    int local = bid - 32768;                 // 64 blocks: 2 sides x 8 k x 4 n
    int side = local >> 5; int r = local & 31;
    const float* W1 = side ? P.pW1b : P.pW1a;
    const float* b1 = side ? P.pb1b : P.pb1a;
    float* v = side ? P.pvb : P.pva;
    int n = (r & 3) * 256 + tid;
    int k0 = (r >> 2) * 256;
    float acc = (k0 == 0) ? b1[n] : 0.0f;
#pragma unroll 8
    for (int k = 0; k < 256; ++k)
      acc = fmaf(P.pb2[k0 + k], W1[(size_t)(k0 + k) * HHALF + n], acc);
    atomicAdd(&v[n], acc);
  }
}

// ---------------- Skinny logits, 5 routers batched ----------------
// Jobs 3/4 read two split-K partials and apply the deferred ReLU.
struct LJob { const float* Y; const float* Y2; const float* W2;
              const float* b2; float* L; int K; int relu; };
struct LJobs { LJob j[5]; };
__global__ __launch_bounds__(256) void logits_kernel(LJobs P) {
  const LJob J = P.j[blockIdx.x >> 8];
  const int blk = blockIdx.x & 255;
  const int tid = threadIdx.x;
  const int wid = tid >> 6, lane = tid & 63;
  const int e = lane & 15;
  const int kq = lane >> 4;
  const int tok0 = blk * 8 + wid * 2;
  const float* y0 = J.Y + (size_t)tok0 * J.K;
  const float* y1 = y0 + J.K;
  const float* z0 = J.Y2 + (size_t)tok0 * J.K;
  const float* z1 = z0 + J.K;
  const int KQ = J.K >> 2;
  const int kbase = kq * KQ;
  float a0 = 0.f, a1 = 0.f;
  if (J.relu) {
#pragma unroll 8
    for (int k = 0; k < KQ; ++k) {
      int kk = kbase + k;
      float w = J.W2[(size_t)kk * EDIM + e];
      float v0 = fmaxf(y0[kk] + z0[kk], 0.0f);
      float v1 = fmaxf(y1[kk] + z1[kk], 0.0f);
      a0 = fmaf(v0, w, a0);
      a1 = fmaf(v1, w, a1);
    }
  } else {
#pragma unroll 8
    for (int k = 0; k < KQ; ++k) {
      int kk = kbase + k;
      float w = J.W2[(size_t)kk * EDIM + e];
      a0 = fmaf(y0[kk], w, a0);
      a1 = fmaf(y1[kk], w, a1);
    }
  }
  a0 += __shfl_xor(a0, 16); a0 += __shfl_xor(a0, 32);
  a1 += __shfl_xor(a1, 16); a1 += __shfl_xor(a1, 32);
  if (lane < 16) {
    float b = J.b2[e];
    J.L[(size_t)tok0 * EDIM + e] = a0 + b;
    J.L[(size_t)(tok0 + 1) * EDIM + e] = a1 + b;
  }
}

// ---------------- Router finalize ----------------
__device__ __forceinline__ void softmax16(const float* __restrict__ L, float* __restrict__ p) {
  float v[16];
  *(float4*)&v[0]  = *(const float4*)&L[0];
  *(float4*)&v[4]  = *(const float4*)&L[4];
  *(float4*)&v[8]  = *(const float4*)&L[8];
  *(float4*)&v[12] = *(const float4*)&L[12];
  float m = v[0];
#pragma unroll
  for (int e = 1; e < 16; ++e) m = fmaxf(m, v[e]);
  float s = 0.0f;
#pragma unroll
  for (int e = 0; e < 16; ++e) { v[e] = expf(v[e] - m); s += v[e]; }
  float inv = 1.0f / s;
#pragma unroll
  for (int e = 0; e < 16; ++e) p[e] = v[e] * inv;
}

__global__ __launch_bounds__(256) void finalize_kernel(
    const float* __restrict__ Lg, const float* __restrict__ Lsi,
    const float* __restrict__ Lsg, const float* __restrict__ Lsc,
    const float* __restrict__ Lsb,
    float* __restrict__ dispatch, float* __restrict__ combine,
    float* __restrict__ router_probs, float* __restrict__ mean_acc) {
  __shared__ float sm[EDIM];
  int tid = threadIdx.x;
  if (tid < EDIM) sm[tid] = 0.0f;
  __syncthreads();

  int tok = blockIdx.x * 256 + tid;
  float pg[16], ps[16], tmp[16], r[16];
  softmax16(Lg + (size_t)tok * EDIM, pg);
  softmax16(Lsi + (size_t)tok * EDIM, ps);
  softmax16(Lsg + (size_t)tok * EDIM, tmp);
#pragma unroll
  for (int e = 0; e < 16; ++e) ps[e] += tmp[e];
  softmax16(Lsc + (size_t)tok * EDIM, tmp);
#pragma unroll
  for (int e = 0; e < 16; ++e) ps[e] += tmp[e];
  softmax16(Lsb + (size_t)tok * EDIM, tmp);
#pragma unroll
  for (int e = 0; e < 16; ++e) ps[e] += tmp[e];

#pragma unroll
  for (int e = 0; e < 16; ++e) {
    float s = ps[e] * 0.5f;
    r[e] = 0.7f * pg[e] + 0.3f * s;
  }

#pragma unroll
  for (int e = 0; e < 16; e += 4) {
    float4 o = {r[e], r[e + 1], r[e + 2], r[e + 3]};
    *(float4*)&router_probs[(size_t)tok * EDIM + e] = o;
  }

#pragma unroll
  for (int e = 0; e < 16; ++e) atomicAdd(&sm[e], r[e]);

  bool used[16];
#pragma unroll
  for (int e = 0; e < 16; ++e) used[e] = false;
  int idx[TOPK];
  float tp[TOPK];
  float tsum = 0.0f;
#pragma unroll
  for (int j = 0; j < TOPK; ++j) {
    float best = -1.0f;
    int bi = 0;
#pragma unroll
    for (int e = 0; e < 16; ++e) {
      bool take = (!used[e]) && (r[e] > best);
      best = take ? r[e] : best;
      bi = take ? e : bi;
    }
    used[bi] = true;
    idx[j] = bi;
    tp[j] = best;
    tsum += best;
  }
  float invt = 1.0f / tsum;
#pragma unroll
  for (int j = 0; j < TOPK; ++j) {
    size_t off = ((size_t)tok * EDIM + idx[j]) * CAPV;
    dispatch[off] = 1.0f;
    combine[off] = tp[j] * invt;
  }

  __syncthreads();
  if (tid < EDIM) atomicAdd(&mean_acc[tid], sm[tid]);
}

__global__ void aux_kernel(const float* __restrict__ mean_acc, float* __restrict__ out_aux) {
  if (threadIdx.x == 0 && blockIdx.x == 0) {
    float s = 0.0f;
    for (int e = 0; e < EDIM; ++e) {
      float m = mean_acc[e] * (1.0f / (float)NTOK);
      s += m * logf(m * (float)EDIM + 1e-9f);
    }
    *out_aux = s;
  }
}

// ---------------- launch ----------------
#define MBYTE (1ull << 20)

extern "C" void kernel_launch(void* const* d_in, const int* in_sizes, int n_in,
                              void* d_out, int out_size, void* d_ws, size_t ws_size,
                              hipStream_t stream) {
  const float* X    = (const float*)d_in[0];
  const float* IMG  = (const float*)d_in[1];
  const float* GEN  = (const float*)d_in[2];
  const float* g_w1 = (const float*)d_in[3];
  const float* g_b1 = (const float*)d_in[4];
  const float* g_w2 = (const float*)d_in[5];
  const float* g_b2 = (const float*)d_in[6];
  const float* m_w1 = (const float*)d_in[7];
  const float* m_b1 = (const float*)d_in[8];
  const float* m_w2 = (const float*)d_in[9];
  const float* m_b2 = (const float*)d_in[10];
  const float* si_w1 = (const float*)d_in[11];
  const float* si_b1 = (const float*)d_in[12];
  const float* si_w2 = (const float*)d_in[13];
  const float* si_b2 = (const float*)d_in[14];
  const float* sg_w1 = (const float*)d_in[15];
  const float* sg_b1 = (const float*)d_in[16];
  const float* sg_w2 = (const float*)d_in[17];
  const float* sg_b2 = (const float*)d_in[18];
  const float* sc_w1 = (const float*)d_in[19];
  const float* sc_b1 = (const float*)d_in[20];
  const float* sc_w2 = (const float*)d_in[21];
  const float* sc_b2 = (const float*)d_in[22];
  const float* sb_w1 = (const float*)d_in[23];
  const float* sb_b1 = (const float*)d_in[24];
  const float* sb_w2 = (const float*)d_in[25];
  const float* sb_b2 = (const float*)d_in[26];

  char* wsb = (char*)d_ws;
  __bf16* Xh    = (__bf16*)(wsb + 0 * MBYTE);
  __bf16* Xl    = (__bf16*)(wsb + 8 * MBYTE);
  __bf16* IMGh  = (__bf16*)(wsb + 16 * MBYTE);
  __bf16* IMGl  = (__bf16*)(wsb + 24 * MBYTE);
  __bf16* GENh  = (__bf16*)(wsb + 32 * MBYTE);
  __bf16* GENl  = (__bf16*)(wsb + 40 * MBYTE);
  __bf16* M2h   = (__bf16*)(wsb + 48 * MBYTE);   // m_w2 elementwise split
  __bf16* M2l   = (__bf16*)(wsb + 56 * MBYTE);
  __bf16* Wm1h  = (__bf16*)(wsb + 64 * MBYTE);
  __bf16* Wm1l  = (__bf16*)(wsb + 72 * MBYTE);
  __bf16* Wg1h  = (__bf16*)(wsb + 80 * MBYTE);
  __bf16* Wg1l  = (__bf16*)(wsb + 88 * MBYTE);
  __bf16* Wsch  = (__bf16*)(wsb + 96 * MBYTE);
  __bf16* Wscl  = (__bf16*)(wsb + 100 * MBYTE);
  __bf16* Wsbh  = (__bf16*)(wsb + 104 * MBYTE);
  __bf16* Wsbl  = (__bf16*)(wsb + 108 * MBYTE);
  __bf16* Wsih  = (__bf16*)(wsb + 112 * MBYTE);
  __bf16* Wsil  = (__bf16*)(wsb + 116 * MBYTE);
  __bf16* Wsgh  = (__bf16*)(wsb + 120 * MBYTE);
  __bf16* Wsgl  = (__bf16*)(wsb + 124 * MBYTE);
  __bf16* H1h   = (__bf16*)(wsb + 128 * MBYTE);
  __bf16* H1l   = (__bf16*)(wsb + 136 * MBYTE);
  __bf16* WPsch = (__bf16*)(wsb + 144 * MBYTE);  // (m_w2@sc_w1)^T split [1024][2048]
  __bf16* WPscl = (__bf16*)(wsb + 148 * MBYTE);
  __bf16* WPsbh = (__bf16*)(wsb + 152 * MBYTE);
  __bf16* WPsbl = (__bf16*)(wsb + 156 * MBYTE);
  float*  YG    = (float*)(wsb + 160 * MBYTE);
  float*  YSI   = (float*)(wsb + 176 * MBYTE);
  float*  YSG   = (float*)(wsb + 184 * MBYTE);
  float*  YSCp0 = (float*)(wsb + 192 * MBYTE);   // split-K partials (bias in p0)
  float*  YSCp1 = (float*)(wsb + 200 * MBYTE);
  float*  YSBp0 = (float*)(wsb + 208 * MBYTE);
  float*  YSBp1 = (float*)(wsb + 216 * MBYTE);
  float* L0 = (float*)(wsb + 224 * MBYTE);
  float* L1 = L0 + NTOK * EDIM;
  float* L2 = L1 + NTOK * EDIM;
  float* L3 = L2 + NTOK * EDIM;
  float* L4 = L3 + NTOK * EDIM;
  float* meanp = L4 + NTOK * EDIM;
  float* zbias = meanp + EDIM;         // 2048 zeros (bias for W'/kh1 jobs)
  float* vsc = zbias + GK;
  float* vsb = vsc + HHALF;

  float* dispatch = (float*)d_out;
  float* combine = dispatch + (size_t)NTOK * EDIM * CAPV;
  float* rp = combine + (size_t)NTOK * EDIM * CAPV;
  float* aux = rp + (size_t)NTOK * EDIM;

  hipMemsetAsync(d_out, 0, (size_t)out_size * sizeof(float), stream);
  // zero meanp + zbias + vsc + vsb (contiguous)
  hipMemsetAsync(meanp, 0, (EDIM + GK + 2 * HHALF) * sizeof(float), stream);

  dim3 blk(256);

  // 1) fused prep: splits + transpose-splits + prebias (one dispatch)
  {
    PrepArgs p;
    p.s[0] = {X, Xh, Xl};
    p.s[1] = {IMG, IMGh, IMGl};
    p.s[2] = {GEN, GENh, GENl};
    p.s[3] = {m_w2, M2h, M2l};
    p.t[0] = {m_w1, Wm1h, Wm1l, HDIM};
    p.t[1] = {g_w1, Wg1h, Wg1l, HDIM};
    p.t[2] = {sc_w1, Wsch, Wscl, HHALF};
    p.t[3] = {sb_w1, Wsbh, Wsbl, HHALF};
    p.t[4] = {si_w1, Wsih, Wsil, HHALF};
    p.t[5] = {sg_w1, Wsgh, Wsgl, HHALF};
    p.pb2 = m_b2;
    p.pW1a = sc_w1; p.pb1a = sc_b1; p.pva = vsc;
    p.pW1b = sb_w1; p.pb1b = sb_b1; p.pvb = vsb;
    prep<<<32832, blk, 0, stream>>>(p);
  }

  // 2) GEMM stage A: 6 independent jobs, exactly 256 blocks (3-phase kernel)
  {
    GJobsA g;
    g.j[0] = {Xh, Xl, Wm1h, Wm1l, m_b1, nullptr, H1h, H1l, 1, HDIM, 0};      // 64
    g.j[1] = {Xh, Xl, Wg1h, Wg1l, g_b1, YG, nullptr, nullptr, 1, HDIM, 64};  // 64
    g.j[2] = {IMGh, IMGl, Wsih, Wsil, si_b1, YSI, nullptr, nullptr, 1, HHALF, 128}; // 32
    g.j[3] = {GENh, GENl, Wsgh, Wsgl, sg_b1, YSG, nullptr, nullptr, 1, HHALF, 160}; // 32
    g.j[4] = {Wsch, Wscl, M2h, M2l, zbias, nullptr, WPsch, WPscl, 0, HDIM, 192};    // 32 (M=1024)
    g.j[5] = {Wsbh, Wsbl, M2h, M2l, zbias, nullptr, WPsbh, WPsbl, 0, HDIM, 224};    // 32 (M=1024)
    gemm_phased<<<256, dim3(512), 0, stream>>>(g);
  }

  // 3) GEMM stage B': split-K=2 partials (relu deferred to logits), 512 blocks
  {
    GJobs g;
    g.j[0] = {H1h, H1l, WPsch, WPscl, vsc, YSCp0, nullptr, nullptr, 0, HHALF, 0, 1024};
    g.j[1] = {H1h + 1024, H1l + 1024, WPsch + 1024, WPscl + 1024, zbias, YSCp1,
              nullptr, nullptr, 0, HHALF, 128, 1024};
    g.j[2] = {H1h, H1l, WPsbh, WPsbl, vsb, YSBp0, nullptr, nullptr, 0, HHALF, 256, 1024};
    g.j[3] = {H1h + 1024, H1l + 1024, WPsbh + 1024, WPsbl + 1024, zbias, YSBp1,
              nullptr, nullptr, 0, HHALF, 384, 1024};
    g.njobs = 4;
    gemm_split<<<512, blk, 0, stream>>>(g);
  }

  // 4) batched logits (all 5 routers; sc/sb sum partials + relu)
  {
    LJobs l;
    l.j[0] = {YG, YG, g_w2, g_b2, L0, HDIM, 0};
    l.j[1] = {YSI, YSI, si_w2, si_b2, L1, HHALF, 0};
    l.j[2] = {YSG, YSG, sg_w2, sg_b2, L2, HHALF, 0};
    l.j[3] = {YSCp0, YSCp1, sc_w2, sc_b2, L3, HHALF, 1};
    l.j[4] = {YSBp0, YSBp1, sb_w2, sb_b2, L4, HHALF, 1};
    logits_kernel<<<5 * 256, blk, 0, stream>>>(l);
  }

  // 5) finalize + aux
  finalize_kernel<<<NTOK / 256, blk, 0, stream>>>(L0, L1, L2, L3, L4,
                                                  dispatch, combine, rp, meanp);
  aux_kernel<<<1, 64, 0, stream>>>(meanp, aux);
}